// Round 10
// baseline (217.156 us; speedup 1.0000x reference)
//
#include <hip/hip_runtime.h>
#include <hip/hip_bf16.h>

// Cross-attention, bf16 MFMA path. B=8 T=256 S=4096 E=512 KV=768 H=8 D=64.
// ws (113.5 MiB):
//   kbuf  [0,32)MiB   bf16 [b][h][s][d]
//   vbuf  [32,64)MiB  bf16 [b][h][d][s]
//   ctxb  [64,112)MiB bf16 context (dead after gemm_kv) -- aliased below:
//     qbuf [64,66)  obuf [66,68)  po [68,84)  ml [84,84.5)
//   wkvb  [112,113.5)MiB bf16 Wkv
// Launch: cvt_wkv cvt_ctx gemm_kv gemm_bt<0>(Q) attn merge gemm_bt<2>(O).

typedef float f32x4 __attribute__((ext_vector_type(4)));
typedef __bf16 bf16x8 __attribute__((ext_vector_type(8)));
typedef unsigned short u16x8 __attribute__((ext_vector_type(8)));
typedef unsigned short u16x4 __attribute__((ext_vector_type(4)));
typedef unsigned int u32x4 __attribute__((ext_vector_type(4)));

static __device__ __forceinline__ unsigned short f2bf(float f) {
  return __builtin_bit_cast(unsigned short, (__bf16)f);   // v_cvt (RNE)
}
static __device__ __forceinline__ unsigned pk2(float lo, float hi) {
  return (unsigned)f2bf(lo) | ((unsigned)f2bf(hi) << 16);
}
static __device__ __forceinline__ f32x4 mfma16(bf16x8 a, bf16x8 b, f32x4 c) {
  return __builtin_amdgcn_mfma_f32_16x16x32_bf16(a, b, c, 0, 0, 0);
}
static __device__ __forceinline__ bf16x8 ld_frag(const unsigned short* lds, int byteOff) {
  return __builtin_bit_cast(bf16x8, *(const u16x8*)((const char*)lds + byteOff));
}
static __device__ __forceinline__ void gll16(const void* g, void* l) {
  __builtin_amdgcn_global_load_lds((__attribute__((address_space(1))) void*)(void*)g,
                                   (__attribute__((address_space(3))) void*)l, 16, 0, 0);
}
// chunk swizzle for [row][4x16B] bf16 tiles; conflict-free write+read b128
// (measured SQ_LDS_BANK_CONFLICT==0, rounds 4-8). Period 16 in row.
static __device__ __forceinline__ int swz4(int row) {
  return (row + (row >> 1)) & 3;
}

// ctx fp32 -> bf16: exact shape 25165824 elems = 2048 blk x 256 thr x 3 iters x 16.
// NT loads (read-once), normal stores (ctxb re-read by gemm_kv via L3).
__global__ __launch_bounds__(256) void cvt_ctx(const float* __restrict__ in,
                                               unsigned short* __restrict__ out) {
  const long t = blockIdx.x * 256L + threadIdx.x;
#pragma unroll
  for (int it = 0; it < 3; ++it) {
    const long c = t + it * 524288L;
    const f32x4* p = (const f32x4*)(in + c * 16);
    f32x4 a = __builtin_nontemporal_load(p);
    f32x4 b = __builtin_nontemporal_load(p + 1);
    f32x4 cc = __builtin_nontemporal_load(p + 2);
    f32x4 d = __builtin_nontemporal_load(p + 3);
    u16x8 o0 = { f2bf(a[0]), f2bf(a[1]), f2bf(a[2]), f2bf(a[3]),
                 f2bf(b[0]), f2bf(b[1]), f2bf(b[2]), f2bf(b[3]) };
    u16x8 o1 = { f2bf(cc[0]), f2bf(cc[1]), f2bf(cc[2]), f2bf(cc[3]),
                 f2bf(d[0]), f2bf(d[1]), f2bf(d[2]), f2bf(d[3]) };
    *(u16x8*)(out + c * 16) = o0;
    *(u16x8*)(out + c * 16 + 8) = o1;
  }
}

// Wkv fp32 -> bf16 (3 MiB)
__global__ __launch_bounds__(256) void cvt_bf16(const float* __restrict__ in,
                                                unsigned short* __restrict__ out, int n8) {
  int i = blockIdx.x * 256 + threadIdx.x;
  if (i >= n8) return;
  const f32x4* p = (const f32x4*)(in + (long)i * 8);
  f32x4 a = p[0], b = p[1];
  u16x8 o = { f2bf(a[0]), f2bf(a[1]), f2bf(a[2]), f2bf(a[3]),
              f2bf(b[0]), f2bf(b[1]), f2bf(b[2]), f2bf(b[3]) };
  *(u16x8*)(out + (long)i * 8) = o;
}

// KV projection, all-bf16: 128x128 tile, BK=32, global_load_lds w=16,
// triple-buffer, prefetch distance 2, counted vmcnt(4), raw barrier.
// (round-8 proven: 80.8us, MfmaUtil 26.6%, conflicts 0)
__global__ __launch_bounds__(256) void gemm_kv(
    const unsigned short* __restrict__ A, const unsigned short* __restrict__ Bw,
    unsigned short* __restrict__ kbuf, unsigned short* __restrict__ vbuf) {
  constexpr int K = 768;
  constexpr int NT = K / 32;  // 24
  __shared__ unsigned short As[3][128 * 32];
  __shared__ unsigned short Bs[3][128 * 32];
  const int tid = threadIdx.x;
  const int l = tid & 63, wid = tid >> 6;
  const int wr = wid >> 1, wc = wid & 1;
  const int r = l & 15, g = l >> 4;
  // T1: all 8 n-tiles of an m-panel on one XCD
  const int bid = blockIdx.x;
  const int xcd = bid & 7, j = bid >> 3;
  const long m0 = (long)(xcd * 32 + (j >> 3)) * 128;
  const long n0 = (long)(j & 7) * 128;

  const int row0 = tid >> 2, cs = tid & 3;
  const int gk0 = (cs ^ swz4(row0)) * 8;
  const unsigned short* aR = A + (m0 + row0) * K + gk0;
  const unsigned short* bR = Bw + (n0 + row0) * K + gk0;

  auto stage = [&](int sbuf, int kt) {
    const unsigned short* ap = aR + kt * 32;
    const unsigned short* bp = bR + kt * 32;
    gll16(ap,          (char*)As[sbuf] + tid * 16);
    gll16(ap + 64 * K, (char*)As[sbuf] + 4096 + tid * 16);
    gll16(bp,          (char*)Bs[sbuf] + tid * 16);
    gll16(bp + 64 * K, (char*)Bs[sbuf] + 4096 + tid * 16);
  };

  f32x4 acc[4][4] = {};
  stage(0, 0);
  stage(1, 1);
  asm volatile("s_waitcnt vmcnt(4)" ::: "memory");  // tile 0 landed; tile 1 in flight
  __builtin_amdgcn_s_barrier();
  __builtin_amdgcn_sched_barrier(0);

  int cur = 0, nxt2 = 2;
  for (int t = 0; t < NT; ++t) {
    if (t + 2 < NT) stage(nxt2, t + 2);
    bf16x8 af[4], bfr[4];
#pragma unroll
    for (int m = 0; m < 4; ++m) {
      int row = wr * 64 + m * 16 + r;
      af[m] = ld_frag(As[cur], row * 64 + ((g ^ swz4(row)) << 4));
    }
#pragma unroll
    for (int n = 0; n < 4; ++n) {
      int row = wc * 64 + n * 16 + r;
      bfr[n] = ld_frag(Bs[cur], row * 64 + ((g ^ swz4(row)) << 4));
    }
    __builtin_amdgcn_s_setprio(1);
#pragma unroll
    for (int m = 0; m < 4; ++m)
#pragma unroll
      for (int n = 0; n < 4; ++n)
        acc[m][n] = mfma16(af[m], bfr[n], acc[m][n]);
    __builtin_amdgcn_s_setprio(0);
    if (t + 2 < NT) {
      asm volatile("s_waitcnt vmcnt(4)" ::: "memory");
    } else {
      asm volatile("s_waitcnt vmcnt(0)" ::: "memory");
    }
    __builtin_amdgcn_s_barrier();
    __builtin_amdgcn_sched_barrier(0);
    cur = (cur == 2) ? 0 : cur + 1;
    nxt2 = (nxt2 == 2) ? 0 : nxt2 + 1;
  }

  // epilogue: C/D map col=lane&15, row=(lane>>4)*4+reg
#pragma unroll
  for (int m = 0; m < 4; ++m) {
#pragma unroll
    for (int n = 0; n < 4; ++n) {
      f32x4 v = acc[m][n];
      const long rg0 = m0 + wr * 64 + m * 16 + g * 4;
      const long cg = n0 + wc * 64 + n * 16 + r;
      if (cg < 512) {
        int hh = (int)(cg >> 6), dd = (int)(cg & 63);
#pragma unroll
        for (int i = 0; i < 4; ++i) {
          long rg = rg0 + i;
          int bb = (int)(rg >> 12), ss = (int)(rg & 4095);
          kbuf[(((long)(bb * 8 + hh) * 4096 + ss) << 6) + dd] = f2bf(v[i]);
        }
      } else {
        int c2 = (int)(cg - 512);
        int hh = c2 >> 6, dd = c2 & 63;
        int bb = (int)(rg0 >> 12), ss = (int)(rg0 & 4095);
        u16x4 pk = { f2bf(v[0]), f2bf(v[1]), f2bf(v[2]), f2bf(v[3]) };
        *(u16x4*)&vbuf[(((long)(bb * 8 + hh) * 64 + dd) << 12) + ss] = pk;
      }
    }
  }
}

// Small bt-GEMM (Q proj / O proj), reg-staged, dbuf LDS.
template <int OUTMODE, typename TA>
__global__ __launch_bounds__(256) void gemm_bt(
    const TA* __restrict__ A, const float* __restrict__ Bw,
    int M, int N, int K,
    unsigned short* __restrict__ o16a,
    float* __restrict__ oF, const float* __restrict__ bias) {
  __shared__ unsigned short As[2][128 * 32];
  __shared__ unsigned short Bs[2][128 * 32];
  const int tid = threadIdx.x;
  const int l = tid & 63, wid = tid >> 6;
  const int wr = wid >> 1, wc = wid & 1;
  const int r = l & 15, g = l >> 4;
  const long m0 = (long)blockIdx.y * 128, n0 = (long)blockIdx.x * 128;

  const int srow = tid >> 1, sseg = tid & 1;
  const int sz = swz4(srow);
  const int wb0 = srow * 64 + (((sseg * 2) ^ sz) << 4);
  const int wb1 = srow * 64 + (((sseg * 2 + 1) ^ sz) << 4);

  const TA* aptr = A + (m0 + srow) * (long)K + sseg * 16;
  const float* bptr = Bw + (n0 + srow) * (long)K + sseg * 16;

  f32x4 rA[4]; u16x8 rAh[2]; f32x4 rB[4];
  auto loadT = [&](int kt) {
    if constexpr (sizeof(TA) == 4) {
      const f32x4* p = (const f32x4*)(aptr + kt * 32);
      rA[0] = p[0]; rA[1] = p[1]; rA[2] = p[2]; rA[3] = p[3];
    } else {
      const u16x8* p = (const u16x8*)(aptr + kt * 32);
      rAh[0] = p[0]; rAh[1] = p[1];
    }
    const f32x4* q = (const f32x4*)(bptr + kt * 32);
    rB[0] = q[0]; rB[1] = q[1]; rB[2] = q[2]; rB[3] = q[3];
  };
  auto writeT = [&](int sbuf) {
    char* ab = (char*)As[sbuf];
    if constexpr (sizeof(TA) == 4) {
      u32x4 lo = { pk2(rA[0][0], rA[0][1]), pk2(rA[0][2], rA[0][3]),
                   pk2(rA[1][0], rA[1][1]), pk2(rA[1][2], rA[1][3]) };
      u32x4 hi = { pk2(rA[2][0], rA[2][1]), pk2(rA[2][2], rA[2][3]),
                   pk2(rA[3][0], rA[3][1]), pk2(rA[3][2], rA[3][3]) };
      *(u32x4*)(ab + wb0) = lo; *(u32x4*)(ab + wb1) = hi;
    } else {
      *(u16x8*)(ab + wb0) = rAh[0]; *(u16x8*)(ab + wb1) = rAh[1];
    }
    char* bb = (char*)Bs[sbuf];
    u32x4 lo = { pk2(rB[0][0], rB[0][1]), pk2(rB[0][2], rB[0][3]),
                 pk2(rB[1][0], rB[1][1]), pk2(rB[1][2], rB[1][3]) };
    u32x4 hi = { pk2(rB[2][0], rB[2][1]), pk2(rB[2][2], rB[2][3]),
                 pk2(rB[3][0], rB[3][1]), pk2(rB[3][2], rB[3][3]) };
    *(u32x4*)(bb + wb0) = lo; *(u32x4*)(bb + wb1) = hi;
  };

  f32x4 acc[4][4] = {};
  const int nt = K >> 5;
  loadT(0); writeT(0);
  __syncthreads();
  int buf = 0;
  for (int t = 0; t < nt; ++t) {
    if (t + 1 < nt) loadT(t + 1);
    bf16x8 af[4], bfr[4];
#pragma unroll
    for (int m = 0; m < 4; ++m) {
      int row = wr * 64 + m * 16 + r;
      af[m] = ld_frag(As[buf], row * 64 + ((g ^ swz4(row)) << 4));
    }
#pragma unroll
    for (int n = 0; n < 4; ++n) {
      int row = wc * 64 + n * 16 + r;
      bfr[n] = ld_frag(Bs[buf], row * 64 + ((g ^ swz4(row)) << 4));
    }
#pragma unroll
    for (int m = 0; m < 4; ++m)
#pragma unroll
      for (int n = 0; n < 4; ++n)
        acc[m][n] = mfma16(af[m], bfr[n], acc[m][n]);
    if (t + 1 < nt) writeT(buf ^ 1);
    __syncthreads();
    buf ^= 1;
  }

#pragma unroll
  for (int m = 0; m < 4; ++m) {
#pragma unroll
    for (int n = 0; n < 4; ++n) {
      f32x4 v = acc[m][n];
      const long rg0 = m0 + wr * 64 + m * 16 + g * 4;
      const long cg = n0 + wc * 64 + n * 16 + r;
      if constexpr (OUTMODE == 0) {
#pragma unroll
        for (int i = 0; i < 4; ++i) {
          long rg = rg0 + i;
          int bb = (int)(rg >> 8), tt = (int)(rg & 255);
          int hh = (int)(cg >> 6), dd = (int)(cg & 63);
          o16a[(((long)(bb * 8 + hh) * 256 + tt) << 6) + dd] = f2bf(v[i]);
        }
      } else {
#pragma unroll
        for (int i = 0; i < 4; ++i) {
          long rg = rg0 + i;
          oF[rg * (long)N + cg] = v[i] + bias[cg];
        }
      }
    }
  }
}

// Flash attention, S-split x4 (proven).
__global__ __launch_bounds__(256) void attn_fwd(
    const unsigned short* __restrict__ qbuf,
    const unsigned short* __restrict__ kbuf,
    const unsigned short* __restrict__ vbuf,
    const int* __restrict__ mask,
    float* __restrict__ po, float* __restrict__ ml) {
  __shared__ unsigned short Ks[2][64 * 64];
  __shared__ unsigned short Vs[2][64 * 64];
  __shared__ unsigned short Ps[4][16 * 64];
  const int tid = threadIdx.x;
  const int l = tid & 63, w = tid >> 6;
  const int r = l & 15, g = l >> 4;
  const int bid = blockIdx.x;
  const int j = (bid & 7) * 128 + (bid >> 3);
  const int qt = j & 3, bh = (j >> 2) & 63, sp = j >> 8;

  const unsigned short* qrow = qbuf + (((long)bh * 256) + qt * 64 + w * 16 + r) * 64;
  const bf16x8 qf0 = __builtin_bit_cast(bf16x8, *(const u16x8*)(qrow + g * 8));
  const bf16x8 qf1 = __builtin_bit_cast(bf16x8, *(const u16x8*)(qrow + 32 + g * 8));

  f32x4 accO[4] = {};
  float mrow[4] = { -1e30f, -1e30f, -1e30f, -1e30f };
  float lrow[4] = {};
  const float SCL = 0.125f * 1.44269504088896340736f;

  const int s_base = sp * 1024;
  const unsigned short* kbase = kbuf + ((long)bh * 4096 + s_base) * 64;
  const unsigned short* vbase = vbuf + ((long)bh * 64) * 4096 + s_base;
  const int* mbase = mask + (bh >> 3) * 4096 + s_base;

  const int st_row = tid >> 3, st_c = tid & 7;
  auto stage = [&](int sbuf, int t0) {
#pragma unroll
    for (int p = 0; p < 2; ++p) {
      int row = p * 32 + st_row;
      int colb = (st_c * 16) ^ ((row & 7) << 4);
      int ldsOff = (p * 256 + tid) * 16;
      gll16(kbase + (long)(t0 + row) * 64 + (colb >> 1), (char*)Ks[sbuf] + ldsOff);
      gll16(vbase + (long)row * 4096 + t0 + (colb >> 1), (char*)Vs[sbuf] + ldsOff);
    }
  };

  stage(0, 0);
  asm volatile("s_waitcnt vmcnt(0)" ::: "memory");
  __builtin_amdgcn_s_barrier();
  __builtin_amdgcn_sched_barrier(0);

  int buf = 0;
  for (int it = 0; it < 16; ++it) {
    if (it + 1 < 16) stage(buf ^ 1, (it + 1) * 64);

    f32x4 sc[4] = {};
    __builtin_amdgcn_s_setprio(1);
#pragma unroll
    for (int nf = 0; nf < 4; ++nf) {
      int row = nf * 16 + r;
      int swz = (row & 7) << 4;
      bf16x8 k0 = ld_frag(Ks[buf], row * 128 + ((g * 16) ^ swz));
      bf16x8 k1 = ld_frag(Ks[buf], row * 128 + ((g * 16 + 64) ^ swz));
      sc[nf] = mfma16(qf0, k0, sc[nf]);
      sc[nf] = mfma16(qf1, k1, sc[nf]);
    }
    __builtin_amdgcn_s_setprio(0);

    float s[4][4];
#pragma unroll
    for (int nf = 0; nf < 4; ++nf) {
      bool mk = mbase[it * 64 + nf * 16 + r] != 0;
#pragma unroll
      for (int i = 0; i < 4; ++i) s[nf][i] = mk ? -1e30f : sc[nf][i] * SCL;
    }

    float tm[4], pr[4][4], rs[4], corr[4];
#pragma unroll
    for (int i = 0; i < 4; ++i) {
      tm[i] = fmaxf(fmaxf(s[0][i], s[1][i]), fmaxf(s[2][i], s[3][i]));
#pragma unroll
      for (int off = 1; off < 16; off <<= 1)
        tm[i] = fmaxf(tm[i], __shfl_xor(tm[i], off));
      float mn = fmaxf(mrow[i], tm[i]);
      corr[i] = exp2f(mrow[i] - mn);
      mrow[i] = mn;
      rs[i] = 0.f;
    }
#pragma unroll
    for (int nf = 0; nf < 4; ++nf)
#pragma unroll
      for (int i = 0; i < 4; ++i) {
        pr[nf][i] = exp2f(s[nf][i] - mrow[i]);
        rs[i] += pr[nf][i];
      }
#pragma unroll
    for (int i = 0; i < 4; ++i) {
#pragma unroll
      for (int off = 1; off < 16; off <<= 1)
        rs[i] += __shfl_xor(rs[i], off);
      lrow[i] = lrow[i] * corr[i] + rs[i];
    }
    f32x4 cv = { corr[0], corr[1], corr[2], corr[3] };
#pragma unroll
    for (int nf = 0; nf < 4; ++nf) accO[nf] *= cv;

    unsigned short* Pw = Ps[w];
#pragma unroll
    for (int nf = 0; nf < 4; ++nf)
#pragma unroll
      for (int i = 0; i < 4; ++i) {
        int prow = g * 4 + i;
        int pb = prow * 128 + ((((nf * 16 + r) * 2)) ^ ((prow & 7) << 4));
        *(unsigned short*)((char*)Pw + pb) = f2bf(pr[nf][i]);
      }
    asm volatile("s_waitcnt lgkmcnt(0)" ::: "memory");
    bf16x8 pf0 = ld_frag(Pw, r * 128 + ((g * 16) ^ ((r & 7) << 4)));
    bf16x8 pf1 = ld_frag(Pw, r * 128 + ((g * 16 + 64) ^ ((r & 7) << 4)));

    __builtin_amdgcn_s_setprio(1);
#pragma unroll
    for (int nf = 0; nf < 4; ++nf) {
      int row = nf * 16 + r;
      int swz = (row & 7) << 4;
      bf16x8 v0 = ld_frag(Vs[buf], row * 128 + ((g * 16) ^ swz));
      bf16x8 v1 = ld_frag(Vs[buf], row * 128 + ((g * 16 + 64) ^ swz));
      accO[nf] = mfma16(pf0, v0, accO[nf]);
      accO[nf] = mfma16(pf1, v1, accO[nf]);
    }
    __builtin_amdgcn_s_setprio(0);

    asm volatile("s_waitcnt vmcnt(0)" ::: "memory");
    __builtin_amdgcn_s_barrier();
    __builtin_amdgcn_sched_barrier(0);
    buf ^= 1;
  }

  const long rowg = (long)bh * 256 + qt * 64 + w * 16 + g * 4;
#pragma unroll
  for (int nf = 0; nf < 4; ++nf)
#pragma unroll
    for (int i = 0; i < 4; ++i)
      po[((long)sp * 16384 + rowg + i) * 64 + nf * 16 + r] = accO[nf][i];
  if (r == 0) {
#pragma unroll
    for (int i = 0; i < 4; ++i) {
      ml[((long)sp * 16384 + rowg + i) * 2 + 0] = mrow[i];
      ml[((long)sp * 16384 + rowg + i) * 2 + 1] = lrow[i];
    }
  }
}

// Merge 4 split partials -> obuf bf16 [b][t][h*64+d]
__global__ __launch_bounds__(256) void attn_merge(
    const float* __restrict__ po, const float* __restrict__ ml,
    unsigned short* __restrict__ obuf) {
  const int idx = blockIdx.x * 256 + threadIdx.x;
  const int row = idx >> 2, dc = (idx & 3) << 4;
  float ms[4], ls[4], mx = -1e30f;
#pragma unroll
  for (int sp = 0; sp < 4; ++sp) {
    ms[sp] = ml[((long)sp * 16384 + row) * 2 + 0];
    ls[sp] = ml[((long)sp * 16384 + row) * 2 + 1];
    mx = fmaxf(mx, ms[sp]);
  }
  float lsum = 0.f, wg[4];
#pragma unroll
  for (int sp = 0; sp < 4; ++sp) { wg[sp] = exp2f(ms[sp] - mx); lsum += wg[sp] * ls[sp]; }
  const float inv = 1.f / lsum;
  f32x4 o[4] = {};
#pragma unroll
  for (int sp = 0; sp < 4; ++sp) {
    const f32x4* p = (const f32x4*)(po + ((long)sp * 16384 + row) * 64 + dc);
#pragma unroll
    for (int c = 0; c < 4; ++c) o[c] += wg[sp] * p[c];
  }
  u16x8 o0, o1;
#pragma unroll
  for (int k = 0; k < 8; ++k) {
    o0[k] = f2bf(o[k >> 2][k & 3] * inv);
    o1[k] = f2bf(o[2 + (k >> 2)][k & 3] * inv);
  }
  const long off = (((long)((row >> 11) * 256 + (row & 255))) << 9) + ((row >> 8) & 7) * 64 + dc;
  *(u16x8*)&obuf[off] = o0;
  *(u16x8*)&obuf[off + 8] = o1;
}

extern "C" void kernel_launch(void* const* d_in, const int* in_sizes, int n_in,
                              void* d_out, int out_size, void* d_ws, size_t ws_size,
                              hipStream_t stream) {
  (void)in_sizes; (void)n_in; (void)out_size; (void)ws_size;
  const float* x    = (const float*)d_in[0];
  const float* ctx  = (const float*)d_in[1];
  const int*   mask = (const int*)d_in[2];
  const float* Wq   = (const float*)d_in[3];
  const float* Wkv  = (const float*)d_in[4];
  const float* Wo   = (const float*)d_in[5];
  const float* bo   = (const float*)d_in[6];
  float* out = (float*)d_out;

  char* ws = (char*)d_ws;
  const size_t MiB = 1024 * 1024;
  unsigned short* kbuf = (unsigned short*)(ws);
  unsigned short* vbuf = (unsigned short*)(ws + 32 * MiB);
  unsigned short* ctxb = (unsigned short*)(ws + 64 * MiB);   // dead after gemm_kv
  unsigned short* qbuf = (unsigned short*)(ws + 64 * MiB);   // aliases ctxb (after)
  unsigned short* obuf = (unsigned short*)(ws + 66 * MiB);
  float* po = (float*)(ws + 68 * MiB);
  float* ml = (float*)(ws + 84 * MiB);
  unsigned short* wkvb = (unsigned short*)(ws + 112 * MiB);

  // fp32 -> bf16
  cvt_bf16<<<dim3(384), 256, 0, stream>>>(Wkv, wkvb, 98304);
  cvt_ctx<<<dim3(2048), 256, 0, stream>>>(ctx, ctxb);
  // KV projection: M=32768 N=1024 K=768, bf16 gll path, tbuf counted-vmcnt
  gemm_kv<<<dim3(2048), 256, 0, stream>>>(ctxb, wkvb, kbuf, vbuf);
  // Q projection: M=2048 N=512 K=512 (after gemm_kv; qbuf aliases ctxb)
  gemm_bt<0, float><<<dim3(4, 16), 256, 0, stream>>>(
      x, Wq, 2048, 512, 512, qbuf, nullptr, nullptr);
  // attention: 4 S-splits x 64 bh x 4 qtiles
  attn_fwd<<<dim3(1024), 256, 0, stream>>>(qbuf, kbuf, vbuf, mask, po, ml);
  attn_merge<<<dim3(256), 256, 0, stream>>>(po, ml, obuf);
  // output projection + bias
  gemm_bt<2, unsigned short><<<dim3(4, 16), 256, 0, stream>>>(
      obuf, Wo, 2048, 512, 512, nullptr, out, bo);
}

// Round 11
// 190.601 us; speedup vs baseline: 1.1393x; 1.1393x over previous
//
#include <hip/hip_runtime.h>
#include <hip/hip_bf16.h>

// Cross-attention, bf16 MFMA path. B=8 T=256 S=4096 E=512 KV=768 H=8 D=64.
// ws (113.5 MiB):
//   kbuf  [0,32)MiB   bf16 [b][h][s][d]
//   vbuf  [32,64)MiB  bf16 [b][h][d][s]
//   ctxb  [64,112)MiB bf16 context (dead after gemm_kv) -- aliased below:
//     qbuf [64,66)  obuf [66,68)  po [68,84)  ml [84,84.5)
//   wkvb  [112,113.5)MiB bf16 Wkv
// Launch: cvt_all  gemm_kv  gemm_bt<0>(Q)  attn  merge  gemm_bt<2>(O).

typedef float f32x4 __attribute__((ext_vector_type(4)));
typedef __bf16 bf16x8 __attribute__((ext_vector_type(8)));
typedef unsigned short u16x8 __attribute__((ext_vector_type(8)));
typedef unsigned short u16x4 __attribute__((ext_vector_type(4)));
typedef unsigned int u32x4 __attribute__((ext_vector_type(4)));

static __device__ __forceinline__ unsigned short f2bf(float f) {
  return __builtin_bit_cast(unsigned short, (__bf16)f);   // v_cvt (RNE)
}
static __device__ __forceinline__ unsigned pk2(float lo, float hi) {
  return (unsigned)f2bf(lo) | ((unsigned)f2bf(hi) << 16);
}
static __device__ __forceinline__ f32x4 mfma16(bf16x8 a, bf16x8 b, f32x4 c) {
  return __builtin_amdgcn_mfma_f32_16x16x32_bf16(a, b, c, 0, 0, 0);
}
static __device__ __forceinline__ bf16x8 ld_frag(const unsigned short* lds, int byteOff) {
  return __builtin_bit_cast(bf16x8, *(const u16x8*)((const char*)lds + byteOff));
}
static __device__ __forceinline__ void gll16(const void* g, void* l) {
  __builtin_amdgcn_global_load_lds((__attribute__((address_space(1))) void*)(void*)g,
                                   (__attribute__((address_space(3))) void*)l, 16, 0, 0);
}
// chunk swizzle for [row][4x16B] bf16 tiles; conflict-free write+read b128
// (measured SQ_LDS_BANK_CONFLICT==0, rounds 4-10). Period 16 in row.
static __device__ __forceinline__ int swz4(int row) {
  return (row + (row >> 1)) & 3;
}

// fused fp32 -> bf16 for ctx and Wkv; grid-stride (round-8 proven form)
__global__ __launch_bounds__(256) void cvt_all(
    const float* __restrict__ a, unsigned short* __restrict__ ao, long na8,
    const float* __restrict__ b, unsigned short* __restrict__ bo, long nb8) {
  const long total = na8 + nb8;
  for (long i = blockIdx.x * 256L + threadIdx.x; i < total; i += 2048L * 256L) {
    const float* src; unsigned short* dst; long k;
    if (i < na8) { src = a; dst = ao; k = i; }
    else         { src = b; dst = bo; k = i - na8; }
    const f32x4* p = (const f32x4*)(src + k * 8);
    f32x4 x = p[0], y = p[1];
    u16x8 o = { f2bf(x[0]), f2bf(x[1]), f2bf(x[2]), f2bf(x[3]),
                f2bf(y[0]), f2bf(y[1]), f2bf(y[2]), f2bf(y[3]) };
    *(u16x8*)(dst + k * 8) = o;
  }
}

// KV projection, all-bf16: 128x128 tile, BK=32, global_load_lds w=16,
// triple-buffer, prefetch distance 2, counted vmcnt(4), raw barrier
// (round-8 proven core) + NEW: LDS-transpose epilogue for coalesced u16x8 stores.
// Each block is purely K (n0<512) or purely V (n0>=512); each wave's 64x64
// sub-tile sits entirely within one head (wc*64 boundary == head boundary).
__global__ __launch_bounds__(256) void gemm_kv(
    const unsigned short* __restrict__ A, const unsigned short* __restrict__ Bw,
    unsigned short* __restrict__ kbuf, unsigned short* __restrict__ vbuf) {
  constexpr int K = 768;
  constexpr int NT = K / 32;  // 24
  __shared__ unsigned short SH[24576];           // 48KB: As(3x8KB) | Bs(3x8KB)
  auto AsP = [&](int b) { return SH + b * 4096; };
  auto BsP = [&](int b) { return SH + 12288 + b * 4096; };
  const int tid = threadIdx.x;
  const int l = tid & 63, wid = tid >> 6;
  const int wr = wid >> 1, wc = wid & 1;
  const int r = l & 15, g = l >> 4;
  // T1: all 8 n-tiles of an m-panel on one XCD
  const int bid = blockIdx.x;
  const int xcd = bid & 7, j = bid >> 3;
  const long m0 = (long)(xcd * 32 + (j >> 3)) * 128;
  const long n0 = (long)(j & 7) * 128;

  const int row0 = tid >> 2, cs = tid & 3;
  const int gk0 = (cs ^ swz4(row0)) * 8;
  const unsigned short* aR = A + (m0 + row0) * K + gk0;
  const unsigned short* bR = Bw + (n0 + row0) * K + gk0;

  auto stage = [&](int sbuf, int kt) {
    const unsigned short* ap = aR + kt * 32;
    const unsigned short* bp = bR + kt * 32;
    gll16(ap,          (char*)AsP(sbuf) + tid * 16);
    gll16(ap + 64 * K, (char*)AsP(sbuf) + 4096 + tid * 16);
    gll16(bp,          (char*)BsP(sbuf) + tid * 16);
    gll16(bp + 64 * K, (char*)BsP(sbuf) + 4096 + tid * 16);
  };

  f32x4 acc[4][4] = {};
  stage(0, 0);
  stage(1, 1);
  asm volatile("s_waitcnt vmcnt(4)" ::: "memory");  // tile 0 landed; tile 1 in flight
  __builtin_amdgcn_s_barrier();
  __builtin_amdgcn_sched_barrier(0);

  int cur = 0, nxt2 = 2;
  for (int t = 0; t < NT; ++t) {
    if (t + 2 < NT) stage(nxt2, t + 2);
    bf16x8 af[4], bfr[4];
#pragma unroll
    for (int m = 0; m < 4; ++m) {
      int row = wr * 64 + m * 16 + r;
      af[m] = ld_frag(AsP(cur), row * 64 + ((g ^ swz4(row)) << 4));
    }
#pragma unroll
    for (int n = 0; n < 4; ++n) {
      int row = wc * 64 + n * 16 + r;
      bfr[n] = ld_frag(BsP(cur), row * 64 + ((g ^ swz4(row)) << 4));
    }
    __builtin_amdgcn_s_setprio(1);
#pragma unroll
    for (int m = 0; m < 4; ++m)
#pragma unroll
      for (int n = 0; n < 4; ++n)
        acc[m][n] = mfma16(af[m], bfr[n], acc[m][n]);
    __builtin_amdgcn_s_setprio(0);
    if (t + 2 < NT) {
      asm volatile("s_waitcnt vmcnt(4)" ::: "memory");
    } else {
      asm volatile("s_waitcnt vmcnt(0)" ::: "memory");
    }
    __builtin_amdgcn_s_barrier();
    __builtin_amdgcn_sched_barrier(0);
    cur = (cur == 2) ? 0 : cur + 1;
    nxt2 = (nxt2 == 2) ? 0 : nxt2 + 1;
  }

  // ---- epilogue: per-wave 64x64 LDS bounce (stride 66 shorts: <=2-way banks),
  // V transposed in the write, then u16x8 reads -> 1KB-contiguous global stores.
  const bool isK = (n0 < 512);
  unsigned short* ep = SH + wid * 4224;   // 64*66 shorts per wave (16896 <= 24576)
#pragma unroll
  for (int m = 0; m < 4; ++m)
#pragma unroll
    for (int n = 0; n < 4; ++n)
#pragma unroll
      for (int i = 0; i < 4; ++i) {
        int lr = m * 16 + g * 4 + i;    // local C row (s)
        int lc = n * 16 + r;            // local C col (d)
        if (isK) ep[lr * 66 + lc] = f2bf(acc[m][n][i]);
        else     ep[lc * 66 + lr] = f2bf(acc[m][n][i]);  // V: [d][s]
      }
  asm volatile("s_waitcnt lgkmcnt(0)" ::: "memory");  // same-wave write->read

  const int rr0 = l >> 3, cch = l & 7;
  if (isK) {
    const int hh = (int)((n0 + wc * 64) >> 6);
    const long srow0 = m0 + wr * 64;
    const int bb = (int)(srow0 >> 12);
    unsigned short* kb = kbuf + ((long)(bb * 8 + hh) * 4096) * 64;
#pragma unroll
    for (int q = 0; q < 8; ++q) {
      int rr = q * 8 + rr0;                       // local s
      u16x8 vv = *(const u16x8*)&ep[rr * 66 + cch * 8];
      int ss = (int)((srow0 + rr) & 4095);
      *(u16x8*)&kb[(long)ss * 64 + cch * 8] = vv;
    }
  } else {
    const int c2 = (int)(n0 - 512) + wc * 64;
    const int hh = c2 >> 6;                       // d-base = 0 within head
    const long srow0 = m0 + wr * 64;
    const int bb = (int)(srow0 >> 12), ss0 = (int)(srow0 & 4095);
    unsigned short* vb = vbuf + ((long)(bb * 8 + hh) * 64) * 4096;
#pragma unroll
    for (int q = 0; q < 8; ++q) {
      int dd = q * 8 + rr0;                       // local d (LDS row)
      u16x8 vv = *(const u16x8*)&ep[dd * 66 + cch * 8];
      *(u16x8*)&vb[(long)dd * 4096 + ss0 + cch * 8] = vv;
    }
  }
}

// Small bt-GEMM (Q proj / O proj), reg-staged, dbuf LDS.
template <int OUTMODE, typename TA>
__global__ __launch_bounds__(256) void gemm_bt(
    const TA* __restrict__ A, const float* __restrict__ Bw,
    int M, int N, int K,
    unsigned short* __restrict__ o16a,
    float* __restrict__ oF, const float* __restrict__ bias) {
  __shared__ unsigned short As[2][128 * 32];
  __shared__ unsigned short Bs[2][128 * 32];
  const int tid = threadIdx.x;
  const int l = tid & 63, wid = tid >> 6;
  const int wr = wid >> 1, wc = wid & 1;
  const int r = l & 15, g = l >> 4;
  const long m0 = (long)blockIdx.y * 128, n0 = (long)blockIdx.x * 128;

  const int srow = tid >> 1, sseg = tid & 1;
  const int sz = swz4(srow);
  const int wb0 = srow * 64 + (((sseg * 2) ^ sz) << 4);
  const int wb1 = srow * 64 + (((sseg * 2 + 1) ^ sz) << 4);

  const TA* aptr = A + (m0 + srow) * (long)K + sseg * 16;
  const float* bptr = Bw + (n0 + srow) * (long)K + sseg * 16;

  f32x4 rA[4]; u16x8 rAh[2]; f32x4 rB[4];
  auto loadT = [&](int kt) {
    if constexpr (sizeof(TA) == 4) {
      const f32x4* p = (const f32x4*)(aptr + kt * 32);
      rA[0] = p[0]; rA[1] = p[1]; rA[2] = p[2]; rA[3] = p[3];
    } else {
      const u16x8* p = (const u16x8*)(aptr + kt * 32);
      rAh[0] = p[0]; rAh[1] = p[1];
    }
    const f32x4* q = (const f32x4*)(bptr + kt * 32);
    rB[0] = q[0]; rB[1] = q[1]; rB[2] = q[2]; rB[3] = q[3];
  };
  auto writeT = [&](int sbuf) {
    char* ab = (char*)As[sbuf];
    if constexpr (sizeof(TA) == 4) {
      u32x4 lo = { pk2(rA[0][0], rA[0][1]), pk2(rA[0][2], rA[0][3]),
                   pk2(rA[1][0], rA[1][1]), pk2(rA[1][2], rA[1][3]) };
      u32x4 hi = { pk2(rA[2][0], rA[2][1]), pk2(rA[2][2], rA[2][3]),
                   pk2(rA[3][0], rA[3][1]), pk2(rA[3][2], rA[3][3]) };
      *(u32x4*)(ab + wb0) = lo; *(u32x4*)(ab + wb1) = hi;
    } else {
      *(u16x8*)(ab + wb0) = rAh[0]; *(u16x8*)(ab + wb1) = rAh[1];
    }
    char* bb = (char*)Bs[sbuf];
    u32x4 lo = { pk2(rB[0][0], rB[0][1]), pk2(rB[0][2], rB[0][3]),
                 pk2(rB[1][0], rB[1][1]), pk2(rB[1][2], rB[1][3]) };
    u32x4 hi = { pk2(rB[2][0], rB[2][1]), pk2(rB[2][2], rB[2][3]),
                 pk2(rB[3][0], rB[3][1]), pk2(rB[3][2], rB[3][3]) };
    *(u32x4*)(bb + wb0) = lo; *(u32x4*)(bb + wb1) = hi;
  };

  f32x4 acc[4][4] = {};
  const int nt = K >> 5;
  loadT(0); writeT(0);
  __syncthreads();
  int buf = 0;
  for (int t = 0; t < nt; ++t) {
    if (t + 1 < nt) loadT(t + 1);
    bf16x8 af[4], bfr[4];
#pragma unroll
    for (int m = 0; m < 4; ++m) {
      int row = wr * 64 + m * 16 + r;
      af[m] = ld_frag(As[buf], row * 64 + ((g ^ swz4(row)) << 4));
    }
#pragma unroll
    for (int n = 0; n < 4; ++n) {
      int row = wc * 64 + n * 16 + r;
      bfr[n] = ld_frag(Bs[buf], row * 64 + ((g ^ swz4(row)) << 4));
    }
#pragma unroll
    for (int m = 0; m < 4; ++m)
#pragma unroll
      for (int n = 0; n < 4; ++n)
        acc[m][n] = mfma16(af[m], bfr[n], acc[m][n]);
    if (t + 1 < nt) writeT(buf ^ 1);
    __syncthreads();
    buf ^= 1;
  }

#pragma unroll
  for (int m = 0; m < 4; ++m) {
#pragma unroll
    for (int n = 0; n < 4; ++n) {
      f32x4 v = acc[m][n];
      const long rg0 = m0 + wr * 64 + m * 16 + g * 4;
      const long cg = n0 + wc * 64 + n * 16 + r;
      if constexpr (OUTMODE == 0) {
#pragma unroll
        for (int i = 0; i < 4; ++i) {
          long rg = rg0 + i;
          int bb = (int)(rg >> 8), tt = (int)(rg & 255);
          int hh = (int)(cg >> 6), dd = (int)(cg & 63);
          o16a[(((long)(bb * 8 + hh) * 256 + tt) << 6) + dd] = f2bf(v[i]);
        }
      } else {
#pragma unroll
        for (int i = 0; i < 4; ++i) {
          long rg = rg0 + i;
          oF[rg * (long)N + cg] = v[i] + bias[cg];
        }
      }
    }
  }
}

// Flash attention, S-split x4 (proven).
__global__ __launch_bounds__(256) void attn_fwd(
    const unsigned short* __restrict__ qbuf,
    const unsigned short* __restrict__ kbuf,
    const unsigned short* __restrict__ vbuf,
    const int* __restrict__ mask,
    float* __restrict__ po, float* __restrict__ ml) {
  __shared__ unsigned short Ks[2][64 * 64];
  __shared__ unsigned short Vs[2][64 * 64];
  __shared__ unsigned short Ps[4][16 * 64];
  const int tid = threadIdx.x;
  const int l = tid & 63, w = tid >> 6;
  const int r = l & 15, g = l >> 4;
  const int bid = blockIdx.x;
  const int j = (bid & 7) * 128 + (bid >> 3);
  const int qt = j & 3, bh = (j >> 2) & 63, sp = j >> 8;

  const unsigned short* qrow = qbuf + (((long)bh * 256) + qt * 64 + w * 16 + r) * 64;
  const bf16x8 qf0 = __builtin_bit_cast(bf16x8, *(const u16x8*)(qrow + g * 8));
  const bf16x8 qf1 = __builtin_bit_cast(bf16x8, *(const u16x8*)(qrow + 32 + g * 8));

  f32x4 accO[4] = {};
  float mrow[4] = { -1e30f, -1e30f, -1e30f, -1e30f };
  float lrow[4] = {};
  const float SCL = 0.125f * 1.44269504088896340736f;

  const int s_base = sp * 1024;
  const unsigned short* kbase = kbuf + ((long)bh * 4096 + s_base) * 64;
  const unsigned short* vbase = vbuf + ((long)bh * 64) * 4096 + s_base;
  const int* mbase = mask + (bh >> 3) * 4096 + s_base;

  const int st_row = tid >> 3, st_c = tid & 7;
  auto stage = [&](int sbuf, int t0) {
#pragma unroll
    for (int p = 0; p < 2; ++p) {
      int row = p * 32 + st_row;
      int colb = (st_c * 16) ^ ((row & 7) << 4);
      int ldsOff = (p * 256 + tid) * 16;
      gll16(kbase + (long)(t0 + row) * 64 + (colb >> 1), (char*)Ks[sbuf] + ldsOff);
      gll16(vbase + (long)row * 4096 + t0 + (colb >> 1), (char*)Vs[sbuf] + ldsOff);
    }
  };

  stage(0, 0);
  asm volatile("s_waitcnt vmcnt(0)" ::: "memory");
  __builtin_amdgcn_s_barrier();
  __builtin_amdgcn_sched_barrier(0);

  int buf = 0;
  for (int it = 0; it < 16; ++it) {
    if (it + 1 < 16) stage(buf ^ 1, (it + 1) * 64);

    f32x4 sc[4] = {};
    __builtin_amdgcn_s_setprio(1);
#pragma unroll
    for (int nf = 0; nf < 4; ++nf) {
      int row = nf * 16 + r;
      int swz = (row & 7) << 4;
      bf16x8 k0 = ld_frag(Ks[buf], row * 128 + ((g * 16) ^ swz));
      bf16x8 k1 = ld_frag(Ks[buf], row * 128 + ((g * 16 + 64) ^ swz));
      sc[nf] = mfma16(qf0, k0, sc[nf]);
      sc[nf] = mfma16(qf1, k1, sc[nf]);
    }
    __builtin_amdgcn_s_setprio(0);

    float s[4][4];
#pragma unroll
    for (int nf = 0; nf < 4; ++nf) {
      bool mk = mbase[it * 64 + nf * 16 + r] != 0;
#pragma unroll
      for (int i = 0; i < 4; ++i) s[nf][i] = mk ? -1e30f : sc[nf][i] * SCL;
    }

    float tm[4], pr[4][4], rs[4], corr[4];
#pragma unroll
    for (int i = 0; i < 4; ++i) {
      tm[i] = fmaxf(fmaxf(s[0][i], s[1][i]), fmaxf(s[2][i], s[3][i]));
#pragma unroll
      for (int off = 1; off < 16; off <<= 1)
        tm[i] = fmaxf(tm[i], __shfl_xor(tm[i], off));
      float mn = fmaxf(mrow[i], tm[i]);
      corr[i] = exp2f(mrow[i] - mn);
      mrow[i] = mn;
      rs[i] = 0.f;
    }
#pragma unroll
    for (int nf = 0; nf < 4; ++nf)
#pragma unroll
      for (int i = 0; i < 4; ++i) {
        pr[nf][i] = exp2f(s[nf][i] - mrow[i]);
        rs[i] += pr[nf][i];
      }
#pragma unroll
    for (int i = 0; i < 4; ++i) {
#pragma unroll
      for (int off = 1; off < 16; off <<= 1)
        rs[i] += __shfl_xor(rs[i], off);
      lrow[i] = lrow[i] * corr[i] + rs[i];
    }
    f32x4 cv = { corr[0], corr[1], corr[2], corr[3] };
#pragma unroll
    for (int nf = 0; nf < 4; ++nf) accO[nf] *= cv;

    unsigned short* Pw = Ps[w];
#pragma unroll
    for (int nf = 0; nf < 4; ++nf)
#pragma unroll
      for (int i = 0; i < 4; ++i) {
        int prow = g * 4 + i;
        int pb = prow * 128 + ((((nf * 16 + r) * 2)) ^ ((prow & 7) << 4));
        *(unsigned short*)((char*)Pw + pb) = f2bf(pr[nf][i]);
      }
    asm volatile("s_waitcnt lgkmcnt(0)" ::: "memory");
    bf16x8 pf0 = ld_frag(Pw, r * 128 + ((g * 16) ^ ((r & 7) << 4)));
    bf16x8 pf1 = ld_frag(Pw, r * 128 + ((g * 16 + 64) ^ ((r & 7) << 4)));

    __builtin_amdgcn_s_setprio(1);
#pragma unroll
    for (int nf = 0; nf < 4; ++nf) {
      int row = nf * 16 + r;
      int swz = (row & 7) << 4;
      bf16x8 v0 = ld_frag(Vs[buf], row * 128 + ((g * 16) ^ swz));
      bf16x8 v1 = ld_frag(Vs[buf], row * 128 + ((g * 16 + 64) ^ swz));
      accO[nf] = mfma16(pf0, v0, accO[nf]);
      accO[nf] = mfma16(pf1, v1, accO[nf]);
    }
    __builtin_amdgcn_s_setprio(0);

    asm volatile("s_waitcnt vmcnt(0)" ::: "memory");
    __builtin_amdgcn_s_barrier();
    __builtin_amdgcn_sched_barrier(0);
    buf ^= 1;
  }

  const long rowg = (long)bh * 256 + qt * 64 + w * 16 + g * 4;
#pragma unroll
  for (int nf = 0; nf < 4; ++nf)
#pragma unroll
    for (int i = 0; i < 4; ++i)
      po[((long)sp * 16384 + rowg + i) * 64 + nf * 16 + r] = accO[nf][i];
  if (r == 0) {
#pragma unroll
    for (int i = 0; i < 4; ++i) {
      ml[((long)sp * 16384 + rowg + i) * 2 + 0] = mrow[i];
      ml[((long)sp * 16384 + rowg + i) * 2 + 1] = lrow[i];
    }
  }
}

// Merge 4 split partials -> obuf bf16 [b][t][h*64+d]
__global__ __launch_bounds__(256) void attn_merge(
    const float* __restrict__ po, const float* __restrict__ ml,
    unsigned short* __restrict__ obuf) {
  const int idx = blockIdx.x * 256 + threadIdx.x;
  const int row = idx >> 2, dc = (idx & 3) << 4;
  float ms[4], ls[4], mx = -1e30f;
#pragma unroll
  for (int sp = 0; sp < 4; ++sp) {
    ms[sp] = ml[((long)sp * 16384 + row) * 2 + 0];
    ls[sp] = ml[((long)sp * 16384 + row) * 2 + 1];
    mx = fmaxf(mx, ms[sp]);
  }
  float lsum = 0.f, wg[4];
#pragma unroll
  for (int sp = 0; sp < 4; ++sp) { wg[sp] = exp2f(ms[sp] - mx); lsum += wg[sp] * ls[sp]; }
  const float inv = 1.f / lsum;
  f32x4 o[4] = {};
#pragma unroll
  for (int sp = 0; sp < 4; ++sp) {
    const f32x4* p = (const f32x4*)(po + ((long)sp * 16384 + row) * 64 + dc);
#pragma unroll
    for (int c = 0; c < 4; ++c) o[c] += wg[sp] * p[c];
  }
  u16x8 o0, o1;
#pragma unroll
  for (int k = 0; k < 8; ++k) {
    o0[k] = f2bf(o[k >> 2][k & 3] * inv);
    o1[k] = f2bf(o[2 + (k >> 2)][k & 3] * inv);
  }
  const long off = (((long)((row >> 11) * 256 + (row & 255))) << 9) + ((row >> 8) & 7) * 64 + dc;
  *(u16x8*)&obuf[off] = o0;
  *(u16x8*)&obuf[off + 8] = o1;
}

extern "C" void kernel_launch(void* const* d_in, const int* in_sizes, int n_in,
                              void* d_out, int out_size, void* d_ws, size_t ws_size,
                              hipStream_t stream) {
  (void)in_sizes; (void)n_in; (void)out_size; (void)ws_size;
  const float* x    = (const float*)d_in[0];
  const float* ctx  = (const float*)d_in[1];
  const int*   mask = (const int*)d_in[2];
  const float* Wq   = (const float*)d_in[3];
  const float* Wkv  = (const float*)d_in[4];
  const float* Wo   = (const float*)d_in[5];
  const float* bo   = (const float*)d_in[6];
  float* out = (float*)d_out;

  char* ws = (char*)d_ws;
  const size_t MiB = 1024 * 1024;
  unsigned short* kbuf = (unsigned short*)(ws);
  unsigned short* vbuf = (unsigned short*)(ws + 32 * MiB);
  unsigned short* ctxb = (unsigned short*)(ws + 64 * MiB);   // dead after gemm_kv
  unsigned short* qbuf = (unsigned short*)(ws + 64 * MiB);   // aliases ctxb (after)
  unsigned short* obuf = (unsigned short*)(ws + 66 * MiB);
  float* po = (float*)(ws + 68 * MiB);
  float* ml = (float*)(ws + 84 * MiB);
  unsigned short* wkvb = (unsigned short*)(ws + 112 * MiB);

  // fused fp32 -> bf16: ctx (25.17M elems) + Wkv (0.79M elems), grid-stride
  cvt_all<<<dim3(2048), 256, 0, stream>>>(ctx, ctxb, 3145728L, Wkv, wkvb, 98304L);
  // KV projection: M=32768 N=1024 K=768, bf16 gll path, tbuf counted-vmcnt
  gemm_kv<<<dim3(2048), 256, 0, stream>>>(ctxb, wkvb, kbuf, vbuf);
  // Q projection: M=2048 N=512 K=512 (after gemm_kv; qbuf aliases ctxb)
  gemm_bt<0, float><<<dim3(4, 16), 256, 0, stream>>>(
      x, Wq, 2048, 512, 512, qbuf, nullptr, nullptr);
  // attention: 4 S-splits x 64 bh x 4 qtiles
  attn_fwd<<<dim3(1024), 256, 0, stream>>>(qbuf, kbuf, vbuf, mask, po, ml);
  attn_merge<<<dim3(256), 256, 0, stream>>>(po, ml, obuf);
  // output projection + bias
  gemm_bt<2, unsigned short><<<dim3(4, 16), 256, 0, stream>>>(
      obuf, Wo, 2048, 512, 512, nullptr, out, bo);
}